// Round 9
// baseline (2171.166 us; speedup 1.0000x reference)
//
#include <hip/hip_runtime.h>

#define BATCH 256
#define TSTEPS 4096
#define HID 136
#define ODIM 68
#define NT 9          // N tiles: n = 0..143 (tile 8 cols 8..15 dead)
#define KT 5          // K tiles: k = 0..159 (h padded with zeros past 136)
#define THREADS 64    // ONE wave: no barriers anywhere in the t-loop

typedef _Float16 half8 __attribute__((ext_vector_type(8)));
typedef float f32x4 __attribute__((ext_vector_type(4)));
union H8U4 { uint4 u; half8 h; };

__device__ __forceinline__ float fast_tanh(float z) {
    float az = fabsf(z);
    float e = __expf(-2.0f * az);
    float r = (1.0f - e) * __builtin_amdgcn_rcpf(1.0f + e);
    return copysignf(r, z);
}

__global__ __launch_bounds__(THREADS)
void rnn_mfma_1w(const float* __restrict__ x,
                 const float* __restrict__ W_ih,
                 const float* __restrict__ W_hh,
                 const float* __restrict__ b_ih,
                 const float* __restrict__ b_hh,
                 const float* __restrict__ W_fc,
                 const float* __restrict__ b_fc,
                 float* __restrict__ out)
{
    __shared__ __align__(16) _Float16 hS[160];   // h[0..135]; [136..159] stay 0

    const int b    = blockIdx.x;
    const int lane = threadIdx.x;      // 0..63
    const int col  = lane & 15;        // N-col within tile
    const int g    = lane >> 4;        // k-group (A chunk) & write-slot group
    const int kb   = g * 16;           // byte offset of A 16B chunk in K-tile

    // ---- register-resident B-frags: W_hh^T tiles, f16 (9x5x4 = 180 VGPR) ----
    // lane holds B[k = tk*32 + g*8 + j][n = i*16 + col]  (verified by R8)
    half8 bf[NT][KT];
#pragma unroll
    for (int i = 0; i < NT; ++i) {
        const int n = i * 16 + col;
        const bool nv = (n < HID);
#pragma unroll
        for (int tk = 0; tk < KT; ++tk) {
#pragma unroll
            for (int j = 0; j < 8; ++j) {
                const int k = tk * 32 + g * 8 + j;
                bf[i][tk][j] = (_Float16)((nv && k < HID) ? W_hh[n * HID + k] : 0.0f);
            }
        }
    }

    // per-lane owned output rows: tile g -> n0, tile g+4 -> n1, tile 8 -> n2
    const int n0 = g * 16 + col;             // 0..63
    const int n1 = (g + 4) * 16 + col;       // 64..127
    const int n2 = 128 + col;                // 128..143 (valid if col<8, g==0)
    const bool v2 = (g == 0) && (col < 8);
    const float wa0 = W_ih[n0 * 2], wa1 = W_ih[n0 * 2 + 1];
    const float wb0 = W_ih[n1 * 2], wb1 = W_ih[n1 * 2 + 1];
    const float wc0 = v2 ? W_ih[n2 * 2] : 0.f, wc1 = v2 ? W_ih[n2 * 2 + 1] : 0.f;
    const float ba = b_ih[n0] + b_hh[n0];
    const float bb = b_ih[n1] + b_hh[n1];
    const float bc = v2 ? (b_ih[n2] + b_hh[n2]) : 0.f;

    // zero hS — single wave, in-order DS pipe: no barrier needed
    if (lane < 40) ((unsigned int*)hS)[lane] = 0u;
    __syncthreads();   // once, outside the loop (cheap with 1 wave)

    const float2* xg = (const float2*)(x + (size_t)b * (TSTEPS * 2));
    float2 xc = xg[0];

    for (int t = 0; t < TSTEPS; ++t) {
        // A-frags: 5 broadcast ds_read_b128 of OLD h (reads precede writes
        // in program order; same-wave DS ops execute in order -> no sync)
        H8U4 a0, a1, a2, a3, a4;
        a0.u = *(const uint4*)((const char*)hS +   0 + kb);
        a1.u = *(const uint4*)((const char*)hS +  64 + kb);
        a2.u = *(const uint4*)((const char*)hS + 128 + kb);
        a3.u = *(const uint4*)((const char*)hS + 192 + kb);
        a4.u = *(const uint4*)((const char*)hS + 256 + kb);
        // prefetch next x (global, independent of h -> latency hidden)
        const float2 xn = xg[(t + 1) & (TSTEPS - 1)];

        f32x4 c[NT];
#pragma unroll
        for (int i = 0; i < NT; ++i) c[i] = (f32x4){0.f, 0.f, 0.f, 0.f};
#pragma unroll
        for (int i = 0; i < NT; ++i) {
            c[i] = __builtin_amdgcn_mfma_f32_16x16x32_f16(a0.h, bf[i][0], c[i], 0, 0, 0);
            c[i] = __builtin_amdgcn_mfma_f32_16x16x32_f16(a1.h, bf[i][1], c[i], 0, 0, 0);
            c[i] = __builtin_amdgcn_mfma_f32_16x16x32_f16(a2.h, bf[i][2], c[i], 0, 0, 0);
            c[i] = __builtin_amdgcn_mfma_f32_16x16x32_f16(a3.h, bf[i][3], c[i], 0, 0, 0);
            c[i] = __builtin_amdgcn_mfma_f32_16x16x32_f16(a4.h, bf[i][4], c[i], 0, 0, 0);
        }

        // all A rows identical => every lane's c[i][0] == z_raw[i*16 + col]
        float z0 = c[0][0];
        z0 = (g == 1) ? c[1][0] : z0;
        z0 = (g == 2) ? c[2][0] : z0;
        z0 = (g == 3) ? c[3][0] : z0;
        float z1 = c[4][0];
        z1 = (g == 1) ? c[5][0] : z1;
        z1 = (g == 2) ? c[6][0] : z1;
        z1 = (g == 3) ? c[7][0] : z1;
        float z2 = c[8][0];

        z0 += fmaf(xc.x, wa0, fmaf(xc.y, wa1, ba));
        z1 += fmaf(xc.x, wb0, fmaf(xc.y, wb1, bb));
        z2 += fmaf(xc.x, wc0, fmaf(xc.y, wc1, bc));

        hS[n0] = (_Float16)fast_tanh(z0);      // per-lane b16 writes, 2/bank
        hS[n1] = (_Float16)fast_tanh(z1);
        if (v2) hS[n2] = (_Float16)fast_tanh(z2);

        xc = xn;
    }

    // ---- final head: out[b][o] = h . W_fc[o,:] + b_fc[o] (one-time) ----
#pragma unroll
    for (int pass = 0; pass < 2; ++pass) {
        const int o = lane + pass * 64;
        if (o < ODIM) {
            float s = b_fc[o];
#pragma unroll 8
            for (int k = 0; k < HID; ++k)
                s = fmaf((float)hS[k], W_fc[o * HID + k], s);
            out[b * ODIM + o] = s;
        }
    }
}

extern "C" void kernel_launch(void* const* d_in, const int* in_sizes, int n_in,
                              void* d_out, int out_size, void* d_ws, size_t ws_size,
                              hipStream_t stream) {
    const float* x    = (const float*)d_in[0];
    const float* W_ih = (const float*)d_in[1];
    const float* W_hh = (const float*)d_in[2];
    const float* b_ih = (const float*)d_in[3];
    const float* b_hh = (const float*)d_in[4];
    const float* W_fc = (const float*)d_in[5];
    const float* b_fc = (const float*)d_in[6];
    float* out = (float*)d_out;

    rnn_mfma_1w<<<BATCH, THREADS, 0, stream>>>(x, W_ih, W_hh, b_ih, b_hh,
                                               W_fc, b_fc, out);
}

// Round 10
// 1193.507 us; speedup vs baseline: 1.8191x; 1.8191x over previous
//
#include <hip/hip_runtime.h>

#define BATCH 256
#define TSTEPS 4096
#define HID 136
#define HPADH 144     // h padded to 144 f16 (288 B); f16 slots 136..143 stay 0
#define ODIM 68
#define THREADS 256   // 4 waves, exactly 1 per SIMD

typedef _Float16 h2 __attribute__((ext_vector_type(2)));

__device__ __forceinline__ float fast_tanh(float z) {
    float az = fabsf(z);
    float e = __expf(-2.0f * az);
    float r = (1.0f - e) * __builtin_amdgcn_rcpf(1.0f + e);
    return copysignf(r, z);
}

template <int CTRL>
__device__ __forceinline__ float dpp_add(float x) {
    int y = __builtin_amdgcn_update_dpp(0, __float_as_int(x), CTRL, 0xF, 0xF, false);
    return x + __int_as_float(y);
}
// butterfly over 8 consecutive lanes (groups aligned to 8): all 8 get the sum
__device__ __forceinline__ float reduce8(float x) {
    x = dpp_add<0xB1>(x);    // quad_perm xor1
    x = dpp_add<0x4E>(x);    // quad_perm xor2
    x = dpp_add<0x141>(x);   // row_half_mirror (i -> 7-i within 8)
    return x;
}

__device__ __forceinline__ h2 bc_h2(unsigned int u) {
    union { unsigned int u; h2 h; } c; c.u = u; return c.h;
}

// One step: 3 DS reads (2xb128 + b32, R6's aligned k-map), 45 fdot2
// (5 rows x 9 pairs), 5 reduce8, 1 tanh, 1 predicated b16 write.
#define RNN_STEP(HR, HW, T)                                                    \
    {                                                                          \
        float2 xv = *(const float2*)(xs + 2 * (T));                            \
        uint4 u0 = *(const uint4*)((HR) + 16 * ks);                            \
        uint4 u1 = *(const uint4*)((HR) + 16 * ks + 8);                        \
        unsigned int ut = *(const unsigned int*)((HR) + 128 + 2 * ks);         \
        h2 hq[9];                                                              \
        hq[0] = bc_h2(u0.x); hq[1] = bc_h2(u0.y);                              \
        hq[2] = bc_h2(u0.z); hq[3] = bc_h2(u0.w);                              \
        hq[4] = bc_h2(u1.x); hq[5] = bc_h2(u1.y);                              \
        hq[6] = bc_h2(u1.z); hq[7] = bc_h2(u1.w);                              \
        hq[8] = bc_h2(ut);                                                     \
        float a0 = 0.f, a1 = 0.f, a2 = 0.f, a3 = 0.f, a4 = 0.f;                \
        _Pragma("unroll")                                                      \
        for (int q = 0; q < 9; ++q) {                                          \
            a0 = __builtin_amdgcn_fdot2(hq[q], wq[0][q], a0, false);           \
            a1 = __builtin_amdgcn_fdot2(hq[q], wq[1][q], a1, false);           \
            a2 = __builtin_amdgcn_fdot2(hq[q], wq[2][q], a2, false);           \
            a3 = __builtin_amdgcn_fdot2(hq[q], wq[3][q], a3, false);           \
            a4 = __builtin_amdgcn_fdot2(hq[q], wq[4][q], a4, false);           \
        }                                                                      \
        a0 = reduce8(a0);                                                      \
        a1 = reduce8(a1);                                                      \
        a2 = reduce8(a2);                                                      \
        a3 = reduce8(a3);                                                      \
        a4 = reduce8(a4);                                                      \
        float s = a0;                                                          \
        s = (ks == 1) ? a1 : s;                                                \
        s = (ks == 2) ? a2 : s;                                                \
        s = (ks == 3) ? a3 : s;                                                \
        s = (ks == 4) ? a4 : s;                                                \
        float z = fmaf(xv.x, wih0, fmaf(xv.y, wih1, bias)) + s;                \
        float th = fast_tanh(z);                                               \
        if (ks < 4 || (ks == 4 && grp < 2)) (HW)[zrow] = (_Float16)th;         \
    }

__global__ __launch_bounds__(THREADS)
void rnn_fused_kernel(const float* __restrict__ x,
                      const float* __restrict__ W_ih,
                      const float* __restrict__ W_hh,
                      const float* __restrict__ b_ih,
                      const float* __restrict__ b_hh,
                      const float* __restrict__ W_fc,
                      const float* __restrict__ b_fc,
                      float* __restrict__ out)
{
    __shared__ __align__(16) float xs[TSTEPS * 2];     // 32 KB: x[b,:,:]
    __shared__ __align__(16) _Float16 hA[HPADH];
    __shared__ __align__(16) _Float16 hB[HPADH];

    const int b   = blockIdx.x;
    const int tid = threadIdx.x;
    const int wv  = tid >> 6;      // wave 0..3
    const int grp = (tid >> 3) & 3;// group id within wave 0..7 -> use low bits:
    const int g   = tid >> 3;      // global group 0..31 (main rows 4g..4g+3)
    const int ks  = tid & 7;       // k-lane within group

    // extra row for this lane's group parity: 128 + 2*wv + (g&1)  (128..135)
    const int erow = 128 + 2 * wv + (g & 1);

    // ---- persistent W_hh f16 pairs: 5 rows x 9 h2 = 45 VGPR ----
    // k map (R6-proven): q<8 -> k = 16*ks + 2q ; q==8 -> k = 128 + 2*ks
    h2 wq[5][9];
#pragma unroll
    for (int j = 0; j < 5; ++j) {
        const int row = (j < 4) ? (4 * g + j) : erow;
#pragma unroll
        for (int q = 0; q < 9; ++q) {
            const int k = (q < 8) ? (16 * ks + 2 * q) : (128 + 2 * ks);
            const float v0 = (k     < HID) ? W_hh[row * HID + k]     : 0.0f;
            const float v1 = (k + 1 < HID) ? W_hh[row * HID + k + 1] : 0.0f;
            wq[j][q] = h2{(_Float16)v0, (_Float16)v1};
        }
    }
    // lane's finished row: ks 0..3 -> main, ks==4 -> extra, 5..7 dummy
    const int zrow = (ks < 4) ? (4 * g + ks) : (ks == 4) ? erow : (4 * g);
    const float wih0 = W_ih[zrow * 2 + 0];
    const float wih1 = W_ih[zrow * 2 + 1];
    const float bias = b_ih[zrow] + b_hh[zrow];

    // ---- stage x[b] into LDS (coalesced float4); zero h buffers ----
    {
        const float4* xg = (const float4*)(x + (size_t)b * (TSTEPS * 2));
        float4* xl = (float4*)xs;
#pragma unroll
        for (int i = 0; i < TSTEPS * 2 / 4 / THREADS; ++i)
            xl[i * THREADS + tid] = xg[i * THREADS + tid];
    }
    if (tid < HPADH) { hA[tid] = (_Float16)0.f; hB[tid] = (_Float16)0.f; }
    __syncthreads();

    // ---- recurrence, unrolled x2 (fixed buffers), 1 barrier per step ----
    for (int t = 0; t < TSTEPS; t += 2) {
        RNN_STEP(hA, hB, t);
        __syncthreads();
        RNN_STEP(hB, hA, t + 1);
        __syncthreads();
    }
    // TSTEPS even -> final h in hA

    // ---- final head: out[b][o] = h . W_fc[o,:] + b_fc[o] ----
    if (tid < ODIM) {
        const int o = tid;
        float s = b_fc[o];
#pragma unroll 8
        for (int k = 0; k < HID; ++k)
            s = fmaf((float)hA[k], W_fc[o * HID + k], s);
        out[b * ODIM + o] = s;
    }
}

extern "C" void kernel_launch(void* const* d_in, const int* in_sizes, int n_in,
                              void* d_out, int out_size, void* d_ws, size_t ws_size,
                              hipStream_t stream) {
    const float* x    = (const float*)d_in[0];
    const float* W_ih = (const float*)d_in[1];
    const float* W_hh = (const float*)d_in[2];
    const float* b_ih = (const float*)d_in[3];
    const float* b_hh = (const float*)d_in[4];
    const float* W_fc = (const float*)d_in[5];
    const float* b_fc = (const float*)d_in[6];
    float* out = (float*)d_out;

    rnn_fused_kernel<<<BATCH, THREADS, 0, stream>>>(x, W_ih, W_hh, b_ih, b_hh,
                                                    W_fc, b_fc, out);
}